// Round 5
// baseline (564.284 us; speedup 1.0000x reference)
//
#include <hip/hip_runtime.h>
#include <hip/hip_bf16.h>

// MHA forward, round 5: XCD-pinned L2-resident attention + pipelined K-loop,
// exp2 with scale folded into Q, 32q/wave attn_mean.
// S=2048 B=2 E=1024 H=16 D=64. scale = 1/8 (folded: Q *= 0.125*log2e, exp->exp2).
// ws (48.3 MB): xb | qwb | owb | Qp | Kp | Vt | wab | rl | flag
// d_out: out[S,B,E] fp32 (4194304) then attn_mean[B,S,S] fp32 (8388608).

#define Sq 2048
#define Bb 2
#define Ee 1024
#define Hh 16
#define Dd 64
#define LOG2E 1.4426950408889634f
#define QSCALE 0.18033688011112042f   // 0.125 * log2(e)

typedef __attribute__((ext_vector_type(8))) short bhalf8;   // 8 bf16 (4 VGPRs)
typedef __attribute__((ext_vector_type(4))) float f32x4;

__device__ __forceinline__ void gld16(const __hip_bfloat16* g, __hip_bfloat16* l) {
    __builtin_amdgcn_global_load_lds(
        (const __attribute__((address_space(1))) unsigned int*)g,
        (__attribute__((address_space(3))) unsigned int*)l, 16, 0, 0);
}

__device__ __forceinline__ int pkbf(float a, float b) {
    union { __hip_bfloat16 h[2]; int i; } u;
    u.h[0] = __float2bfloat16(a);
    u.h[1] = __float2bfloat16(b);
    return u.i;
}

// ---------------- fused prep: mask scan + fp32->bf16 conversions ----------------
__global__ __launch_bounds__(256) void prep_k(
    const float* __restrict__ x, const float* __restrict__ am,
    const unsigned int* __restrict__ kpm32,
    const float* __restrict__ qkv_w, const float* __restrict__ out_w,
    __hip_bfloat16* __restrict__ xb, __hip_bfloat16* __restrict__ qwb,
    __hip_bfloat16* __restrict__ owb, unsigned int* __restrict__ flag)
{
    const long i = (long)blockIdx.x*256 + threadIdx.x;
    if (i < 1048576) {                       // mask scan (am 1M float4, kpm 1024 u32)
        float4 v = ((const float4*)am)[i];
        bool nz = (v.x != 0.f) | (v.y != 0.f) | (v.z != 0.f) | (v.w != 0.f);
        if (i < 1024) nz |= (kpm32[i] != 0u);
        if (__ballot(nz)) { if ((threadIdx.x & 63) == 0) atomicOr(flag, 1u); }
    } else if (i < 2097152) {                // x conv with [S,B,E]->[B*S][E]
        const long j = i - 1048576;
        const int m = (int)(j >> 8), e4 = (int)(j & 255);
        const int b = m >> 11, s = m & 2047;
        float4 v = ((const float4*)x)[(size_t)(s*Bb + b)*256 + e4];
        union { __hip_bfloat16 h[4]; uint2 u; } o;
        o.h[0]=__float2bfloat16(v.x); o.h[1]=__float2bfloat16(v.y);
        o.h[2]=__float2bfloat16(v.z); o.h[3]=__float2bfloat16(v.w);
        ((uint2*)xb)[(size_t)m*256 + e4] = o.u;
    } else if (i < 2883584) {                // qkv_w conv (786432 float4)
        const long j = i - 2097152;
        float4 v = ((const float4*)qkv_w)[j];
        union { __hip_bfloat16 h[4]; uint2 u; } o;
        o.h[0]=__float2bfloat16(v.x); o.h[1]=__float2bfloat16(v.y);
        o.h[2]=__float2bfloat16(v.z); o.h[3]=__float2bfloat16(v.w);
        ((uint2*)qwb)[j] = o.u;
    } else if (i < 3145728) {                // out_w conv (262144 float4)
        const long j = i - 2883584;
        float4 v = ((const float4*)out_w)[j];
        union { __hip_bfloat16 h[4]; uint2 u; } o;
        o.h[0]=__float2bfloat16(v.x); o.h[1]=__float2bfloat16(v.y);
        o.h[2]=__float2bfloat16(v.z); o.h[3]=__float2bfloat16(v.w);
        ((uint2*)owb)[j] = o.u;
    }
}

// ---------------- GEMM 1: QKV projection, bf16 MFMA, scatter epilogue ----------------
// Q is stored pre-scaled by QSCALE (exp -> exp2 in attention).
__global__ __launch_bounds__(256) void gemm_qkv(
    const __hip_bfloat16* __restrict__ A, const __hip_bfloat16* __restrict__ Bw,
    const float* __restrict__ bias,
    __hip_bfloat16* __restrict__ Qp, __hip_bfloat16* __restrict__ Kp,
    __hip_bfloat16* __restrict__ Vt)
{
    __shared__ __align__(16) __hip_bfloat16 As[128*32];
    __shared__ __align__(16) __hip_bfloat16 Bs[128*32];
    const int t = threadIdx.x;
    const int l = t & 63, lm = l & 15, quad = l >> 4;
    const int w = t >> 6;
    const int mw = (w & 1)*64, nw = (w >> 1)*64;
    const int m0 = blockIdx.y*128, n0 = blockIdx.x*128;

    const int srow = t >> 2;              // 0..63
    const int scol = (t & 3)*8;
    const __hip_bfloat16* ag = A  + (size_t)(m0 + srow)*1024 + scol;
    const __hip_bfloat16* bg = Bw + (size_t)(n0 + srow)*1024 + scol;
    __hip_bfloat16* al = As + t*8;
    __hip_bfloat16* bl = Bs + t*8;

    f32x4 acc[4][4] = {};
    for (int k0 = 0; k0 < 1024; k0 += 32) {
        __syncthreads();
        gld16(ag + k0, al);
        gld16(ag + (size_t)64*1024 + k0, al + 2048);
        gld16(bg + k0, bl);
        gld16(bg + (size_t)64*1024 + k0, bl + 2048);
        __syncthreads();
        bhalf8 af[4], bf[4];
#pragma unroll
        for (int i = 0; i < 4; i++) {
            af[i] = *(const bhalf8*)&As[(mw + i*16 + lm)*32 + quad*8];
            bf[i] = *(const bhalf8*)&Bs[(nw + i*16 + lm)*32 + quad*8];
        }
#pragma unroll
        for (int mf = 0; mf < 4; mf++)
#pragma unroll
            for (int nf = 0; nf < 4; nf++)
                acc[mf][nf] = __builtin_amdgcn_mfma_f32_16x16x32_bf16(af[mf], bf[nf], acc[mf][nf], 0,0,0);
    }
#pragma unroll
    for (int nf = 0; nf < 4; nf++) {
        const int n = n0 + nw + nf*16 + lm;
        const float bz = bias[n];
        const int which = n >> 10, hh = (n >> 6) & 15, dd = n & 63;
#pragma unroll
        for (int mf = 0; mf < 4; mf++)
#pragma unroll
            for (int r = 0; r < 4; r++) {
                const int m = m0 + mw + mf*16 + quad*4 + r;
                const int b2 = m >> 11, s2 = m & 2047;
                const float vf = acc[mf][nf][r] + bz;
                if (which == 0)
                    Qp[((size_t)(b2*Hh + hh)*Sq + s2)*Dd + dd] = __float2bfloat16(vf * QSCALE);
                else if (which == 1)
                    Kp[((size_t)(b2*Hh + hh)*Sq + s2)*Dd + dd] = __float2bfloat16(vf);
                else
                    Vt[((size_t)(b2*Hh + hh)*Dd + dd)*Sq + s2] = __float2bfloat16(vf);
            }
    }
}

// ---------------- Attention core: XCD-pinned, pipelined, S^T + shfl transpose ----------------
// blk = xcd + 8*qt + 256*grp ; bh = grp*8 + xcd -> each XCD holds 4 bh (2 MB K/V) in L2.
__global__ __launch_bounds__(256, 4) void attn_mfma(
    const __hip_bfloat16* __restrict__ Qp, const __hip_bfloat16* __restrict__ Kp,
    const __hip_bfloat16* __restrict__ Vt,
    const float* __restrict__ am, const unsigned char* __restrict__ kpm,
    const unsigned int* __restrict__ flag,
    __hip_bfloat16* __restrict__ wa, float* __restrict__ rlbuf)
{
    const int t = threadIdx.x;
    const int w = t >> 6, l = t & 63, lm = l & 15, quad = l >> 4;
    const int blk = blockIdx.x;
    const int xcd = blk & 7;
    const int qt  = (blk >> 3) & 31;
    const int grp = blk >> 8;                  // 0..3
    const int bh  = grp*8 + xcd;
    const int b   = bh >> 4, h = bh & 15;
    const int q   = qt*64 + w*16 + lm;         // this lane's q row
    const bool masked = (flag[0] != 0u);

    const __hip_bfloat16* qbase = Qp + (size_t)bh*Sq*Dd;
    const __hip_bfloat16* kbase = Kp + (size_t)bh*Sq*Dd;
    const __hip_bfloat16* vbase = Vt + (size_t)bh*Dd*Sq;

    // Q as B-operand (pre-scaled by QSCALE)
    bhalf8 bq[2];
    bq[0] = *(const bhalf8*)(qbase + (size_t)q*Dd + quad*8);
    bq[1] = *(const bhalf8*)(qbase + (size_t)q*Dd + quad*8 + 32);

    f32x4 o[4] = {};
    float lsum = 0.f;

    // preheader: load K tile 0, compute s(0)
    bhalf8 ak[8];
#pragma unroll
    for (int f = 0; f < 2; f++)
#pragma unroll
        for (int j = 0; j < 4; j++)
            ak[f*4+j] = *(const bhalf8*)(kbase + (size_t)(j*16 + lm)*Dd + quad*8 + f*32);
    f32x4 s[4] = {};
#pragma unroll
    for (int f = 0; f < 2; f++)
#pragma unroll
        for (int j = 0; j < 4; j++)
            s[j] = __builtin_amdgcn_mfma_f32_16x16x32_bf16(ak[f*4+j], bq[f], s[j], 0,0,0);

    for (int kt = 0; kt < 32; kt++) {
        const int k0 = kt*64;
        // V^T frags for tile kt (consumed at bottom)
        bhalf8 av[8];
#pragma unroll
        for (int ks = 0; ks < 2; ks++)
#pragma unroll
            for (int nd = 0; nd < 4; nd++)
                av[ks*4+nd] = *(const bhalf8*)(vbase + (size_t)(nd*16+lm)*Sq + k0 + ks*32 + quad*8);
        // K frags for tile kt+1 (in place; consumed by QK below)
        const int k1 = (kt < 31) ? k0 + 64 : k0;
#pragma unroll
        for (int f = 0; f < 2; f++)
#pragma unroll
            for (int j = 0; j < 4; j++)
                ak[f*4+j] = *(const bhalf8*)(kbase + (size_t)(k1 + j*16 + lm)*Dd + quad*8 + f*32);

        // exp2 + pack for tile kt (covers the load latency above)
        int pk[4][2];
#pragma unroll
        for (int j = 0; j < 4; j++) {
            float p[4];
#pragma unroll
            for (int r = 0; r < 4; r++) {
                float sv = s[j][r];
                if (masked) {
                    const int key = k0 + j*16 + quad*4 + r;
                    const float km = kpm[b*Sq + key] ? -1e30f : 0.0f;
                    sv += (am[(size_t)q*Sq + key] + km) * LOG2E;
                }
                p[r] = exp2f(sv);
            }
            lsum += (p[0]+p[1]) + (p[2]+p[3]);
            pk[j][0] = pkbf(p[0], p[1]);
            pk[j][1] = pkbf(p[2], p[3]);
        }

        // scores for tile kt+1
        f32x4 sn[4] = {};
#pragma unroll
        for (int f = 0; f < 2; f++)
#pragma unroll
            for (int j = 0; j < 4; j++)
                sn[j] = __builtin_amdgcn_mfma_f32_16x16x32_bf16(ak[f*4+j], bq[f], sn[j], 0,0,0);

        // PV for tile kt: O^T += V^T · P^T (P^T B-frags via cross-lane pull)
#pragma unroll
        for (int ks = 0; ks < 2; ks++) {
            union { int i[4]; bhalf8 v; } bp;
#pragma unroll
            for (int g = 0; g < 4; g++) {
                const int src = (2*(quad & 1) + (g >> 1))*16 + lm;
                const int t0 = __shfl(pk[2*ks    ][g & 1], src, 64);
                const int t1 = __shfl(pk[2*ks + 1][g & 1], src, 64);
                bp.i[g] = (quad >= 2) ? t1 : t0;
            }
#pragma unroll
            for (int nd = 0; nd < 4; nd++)
                o[nd] = __builtin_amdgcn_mfma_f32_16x16x32_bf16(av[ks*4+nd], bp.v, o[nd], 0,0,0);
        }
#pragma unroll
        for (int j = 0; j < 4; j++) s[j] = sn[j];
    }

    lsum += __shfl_xor(lsum, 16, 64);
    lsum += __shfl_xor(lsum, 32, 64);
    const float rl = 1.0f / lsum;
    if (quad == 0) rlbuf[(size_t)bh*Sq + q] = rl;

#pragma unroll
    for (int nd = 0; nd < 4; nd++) {
        union { __hip_bfloat16 hx[4]; uint2 u; } ou;
#pragma unroll
        for (int r = 0; r < 4; r++) ou.hx[r] = __float2bfloat16(o[nd][r] * rl);
        *(uint2*)(wa + ((size_t)b*Sq + q)*Ee + h*Dd + nd*16 + quad*4) = ou.u;
    }
}

// ---------------- attn_mean: block=(b, 32q, 256 keys); wave = 64 keys, 2 q-subtiles ----------------
__global__ __launch_bounds__(256, 4) void attn_mean_k(
    const __hip_bfloat16* __restrict__ Qp, const __hip_bfloat16* __restrict__ Kp,
    const float* __restrict__ am, const unsigned char* __restrict__ kpm,
    const unsigned int* __restrict__ flag,
    const float* __restrict__ rlbuf, float* __restrict__ attn_mean)
{
    const int t = threadIdx.x;
    const int w = t >> 6, l = t & 63, lm = l & 15, quad = l >> 4;
    const int b  = blockIdx.z;
    const int q0 = blockIdx.y * 32;
    const int kc = blockIdx.x * 256 + w * 64;
    const bool masked = (flag[0] != 0u);

    float macc[2][4][4] = {};

    // load head 0 frags
    bhalf8 aq[2][2], bk[8];
    {
        const __hip_bfloat16* qb = Qp + ((size_t)(b*Hh)*Sq + q0)*Dd;
        const __hip_bfloat16* kb = Kp + (size_t)(b*Hh)*Sq*Dd;
#pragma unroll
        for (int su = 0; su < 2; su++)
#pragma unroll
            for (int f = 0; f < 2; f++)
                aq[su][f] = *(const bhalf8*)(qb + (size_t)(su*16 + lm)*Dd + quad*8 + f*32);
#pragma unroll
        for (int f = 0; f < 2; f++)
#pragma unroll
            for (int j = 0; j < 4; j++)
                bk[f*4+j] = *(const bhalf8*)(kb + (size_t)(kc + j*16 + lm)*Dd + quad*8 + f*32);
    }
    // scores for head 0
    f32x4 s[2][4] = {};
#pragma unroll
    for (int su = 0; su < 2; su++)
#pragma unroll
        for (int f = 0; f < 2; f++)
#pragma unroll
            for (int j = 0; j < 4; j++)
                s[su][j] = __builtin_amdgcn_mfma_f32_16x16x32_bf16(aq[su][f], bk[f*4+j], s[su][j], 0,0,0);

    for (int h = 0; h < Hh; h++) {
        // prefetch next head's frags (in place; current head's QK already consumed them)
        if (h < Hh-1) {
            const __hip_bfloat16* qb = Qp + ((size_t)(b*Hh + h+1)*Sq + q0)*Dd;
            const __hip_bfloat16* kb = Kp + (size_t)(b*Hh + h+1)*Sq*Dd;
#pragma unroll
            for (int su = 0; su < 2; su++)
#pragma unroll
                for (int f = 0; f < 2; f++)
                    aq[su][f] = *(const bhalf8*)(qb + (size_t)(su*16 + lm)*Dd + quad*8 + f*32);
#pragma unroll
            for (int f = 0; f < 2; f++)
#pragma unroll
                for (int j = 0; j < 4; j++)
                    bk[f*4+j] = *(const bhalf8*)(kb + (size_t)(kc + j*16 + lm)*Dd + quad*8 + f*32);
        }
        const int bh = b*Hh + h;
        float rl4[2][4];
#pragma unroll
        for (int su = 0; su < 2; su++)
#pragma unroll
            for (int r = 0; r < 4; r++)
                rl4[su][r] = rlbuf[(size_t)bh*Sq + q0 + su*16 + quad*4 + r] * 0.0625f;

        // exp2 + accumulate for head h (covers prefetch latency)
#pragma unroll
        for (int su = 0; su < 2; su++)
#pragma unroll
            for (int j = 0; j < 4; j++)
#pragma unroll
                for (int r = 0; r < 4; r++) {
                    float sv = s[su][j][r];
                    if (masked) {
                        const int key = kc + j*16 + lm;
                        const float km = kpm[b*Sq + key] ? -1e30f : 0.0f;
                        sv += (am[(size_t)(q0 + su*16 + quad*4 + r)*Sq + key] + km) * LOG2E;
                    }
                    macc[su][j][r] += exp2f(sv) * rl4[su][r];
                }

        // scores for head h+1
        if (h < Hh-1) {
#pragma unroll
            for (int su = 0; su < 2; su++)
#pragma unroll
                for (int j = 0; j < 4; j++) s[su][j] = f32x4{0.f,0.f,0.f,0.f};
#pragma unroll
            for (int su = 0; su < 2; su++)
#pragma unroll
                for (int f = 0; f < 2; f++)
#pragma unroll
                    for (int j = 0; j < 4; j++)
                        s[su][j] = __builtin_amdgcn_mfma_f32_16x16x32_bf16(aq[su][f], bk[f*4+j], s[su][j], 0,0,0);
        }
    }
#pragma unroll
    for (int su = 0; su < 2; su++)
#pragma unroll
        for (int j = 0; j < 4; j++)
#pragma unroll
            for (int r = 0; r < 4; r++)
                attn_mean[((size_t)b*Sq + q0 + su*16 + quad*4 + r)*Sq + kc + j*16 + lm] =
                    macc[su][j][r];
}

// ---------------- GEMM 2: output projection, bf16 MFMA ----------------
__global__ __launch_bounds__(256) void gemm_out(
    const __hip_bfloat16* __restrict__ A, const __hip_bfloat16* __restrict__ Bw,
    const float* __restrict__ bias, float* __restrict__ outp)
{
    __shared__ __align__(16) __hip_bfloat16 As[128*32];
    __shared__ __align__(16) __hip_bfloat16 Bs[128*32];
    const int t = threadIdx.x;
    const int l = t & 63, lm = l & 15, quad = l >> 4;
    const int w = t >> 6;
    const int mw = (w & 1)*64, nw = (w >> 1)*64;
    const int m0 = blockIdx.y*128, n0 = blockIdx.x*128;

    const int srow = t >> 2;
    const int scol = (t & 3)*8;
    const __hip_bfloat16* ag = A  + (size_t)(m0 + srow)*1024 + scol;
    const __hip_bfloat16* bg = Bw + (size_t)(n0 + srow)*1024 + scol;
    __hip_bfloat16* al = As + t*8;
    __hip_bfloat16* bl = Bs + t*8;

    f32x4 acc[4][4] = {};
    for (int k0 = 0; k0 < 1024; k0 += 32) {
        __syncthreads();
        gld16(ag + k0, al);
        gld16(ag + (size_t)64*1024 + k0, al + 2048);
        gld16(bg + k0, bl);
        gld16(bg + (size_t)64*1024 + k0, bl + 2048);
        __syncthreads();
        bhalf8 af[4], bf[4];
#pragma unroll
        for (int i = 0; i < 4; i++) {
            af[i] = *(const bhalf8*)&As[(mw + i*16 + lm)*32 + quad*8];
            bf[i] = *(const bhalf8*)&Bs[(nw + i*16 + lm)*32 + quad*8];
        }
#pragma unroll
        for (int mf = 0; mf < 4; mf++)
#pragma unroll
            for (int nf = 0; nf < 4; nf++)
                acc[mf][nf] = __builtin_amdgcn_mfma_f32_16x16x32_bf16(af[mf], bf[nf], acc[mf][nf], 0,0,0);
    }
#pragma unroll
    for (int nf = 0; nf < 4; nf++) {
        const int n = n0 + nw + nf*16 + lm;
        const float bz = bias[n];
#pragma unroll
        for (int mf = 0; mf < 4; mf++)
#pragma unroll
            for (int r = 0; r < 4; r++) {
                const int m = m0 + mw + mf*16 + quad*4 + r;
                const int b2 = m >> 11, s2 = m & 2047;
                outp[((size_t)s2*Bb + b2)*Ee + n] = acc[mf][nf][r] + bz;
            }
    }
}

extern "C" void kernel_launch(void* const* d_in, const int* in_sizes, int n_in,
                              void* d_out, int out_size, void* d_ws, size_t ws_size,
                              hipStream_t stream) {
    const float*         x         = (const float*)d_in[0];
    const float*         attn_mask = (const float*)d_in[1];
    const unsigned char* kpm       = (const unsigned char*)d_in[2];
    const float*         qkv_w     = (const float*)d_in[3];
    const float*         qkv_b     = (const float*)d_in[4];
    const float*         out_w     = (const float*)d_in[5];
    const float*         out_b     = (const float*)d_in[6];

    float* outp      = (float*)d_out;
    float* attn_mean = outp + 4194304;          // S*B*E

    __hip_bfloat16* xb  = (__hip_bfloat16*)d_ws;     // 8 MB
    __hip_bfloat16* qwb = xb  + 4194304;             // 6 MB
    __hip_bfloat16* owb = qwb + 3145728;             // 2 MB
    __hip_bfloat16* Qp  = owb + 1048576;             // 8 MB (pre-scaled by QSCALE)
    __hip_bfloat16* Kp  = Qp  + 4194304;             // 8 MB
    __hip_bfloat16* Vt  = Kp  + 4194304;             // 8 MB (transposed [B,H,D,S])
    __hip_bfloat16* wab = Vt  + 4194304;             // 8 MB
    float* rlbuf        = (float*)(wab + 4194304);   // 256 KB
    unsigned int* flag  = (unsigned int*)(rlbuf + 65536);

    hipMemsetAsync(flag, 0, sizeof(unsigned int), stream);
    prep_k<<<12288, 256, 0, stream>>>(x, attn_mask, (const unsigned int*)kpm,
                                      qkv_w, out_w, xb, qwb, owb, flag);
    gemm_qkv<<<dim3(24, 32), 256, 0, stream>>>(xb, qwb, qkv_b, Qp, Kp, Vt);
    attn_mfma<<<dim3(1024), 256, 0, stream>>>(Qp, Kp, Vt, attn_mask, kpm, flag, wab, rlbuf);
    attn_mean_k<<<dim3(8, 64, Bb), 256, 0, stream>>>(Qp, Kp, attn_mask, kpm, flag, rlbuf, attn_mean);
    gemm_out<<<dim3(8, 32), 256, 0, stream>>>(wab, owb, out_b, outp);
}

// Round 6
// 391.651 us; speedup vs baseline: 1.4408x; 1.4408x over previous
//
#include <hip/hip_runtime.h>
#include <hip/hip_bf16.h>

// MHA forward, round 6: LDS-staged attention (contiguous global loads,
// swizzled frag-major LDS layout, conflict-free ds_read_b128 frag reads).
// S=2048 B=2 E=1024 H=16 D=64. scale folded into Q (exp2).
// ws (48.3 MB): xb | qwb | owb | Qp | Kp | Vt | wab | rl | flag
// d_out: out[S,B,E] fp32 (4194304) then attn_mean[B,S,S] fp32 (8388608).

#define Sq 2048
#define Bb 2
#define Ee 1024
#define Hh 16
#define Dd 64
#define LOG2E 1.4426950408889634f
#define QSCALE 0.18033688011112042f   // 0.125 * log2(e)

typedef __attribute__((ext_vector_type(8))) short bhalf8;   // 8 bf16 (4 VGPRs)
typedef __attribute__((ext_vector_type(4))) float f32x4;

__device__ __forceinline__ void gld16(const __hip_bfloat16* g, __hip_bfloat16* l) {
    __builtin_amdgcn_global_load_lds(
        (const __attribute__((address_space(1))) unsigned int*)g,
        (__attribute__((address_space(3))) unsigned int*)l, 16, 0, 0);
}

__device__ __forceinline__ int pkbf(float a, float b) {
    union { __hip_bfloat16 h[2]; int i; } u;
    u.h[0] = __float2bfloat16(a);
    u.h[1] = __float2bfloat16(b);
    return u.i;
}

// slot s (0..511, 16B chunks of a 64x64 bf16 tile, global-linear) -> swizzled
// frag-major LDS elem offset [f|ks][j|nd][quad][lm][8]
__device__ __forceinline__ int tile_off(int s) {
    return ((s >> 2) & 1) * 2048 + (s >> 7) * 512 + (s & 3) * 128 + ((s >> 3) & 15) * 8;
}

// ---------------- fused prep: mask scan + fp32->bf16 conversions ----------------
__global__ __launch_bounds__(256) void prep_k(
    const float* __restrict__ x, const float* __restrict__ am,
    const unsigned int* __restrict__ kpm32,
    const float* __restrict__ qkv_w, const float* __restrict__ out_w,
    __hip_bfloat16* __restrict__ xb, __hip_bfloat16* __restrict__ qwb,
    __hip_bfloat16* __restrict__ owb, unsigned int* __restrict__ flag)
{
    const long i = (long)blockIdx.x*256 + threadIdx.x;
    if (i < 1048576) {                       // mask scan (am 1M float4, kpm 1024 u32)
        float4 v = ((const float4*)am)[i];
        bool nz = (v.x != 0.f) | (v.y != 0.f) | (v.z != 0.f) | (v.w != 0.f);
        if (i < 1024) nz |= (kpm32[i] != 0u);
        if (__ballot(nz)) { if ((threadIdx.x & 63) == 0) atomicOr(flag, 1u); }
    } else if (i < 2097152) {                // x conv with [S,B,E]->[B*S][E]
        const long j = i - 1048576;
        const int m = (int)(j >> 8), e4 = (int)(j & 255);
        const int b = m >> 11, s = m & 2047;
        float4 v = ((const float4*)x)[(size_t)(s*Bb + b)*256 + e4];
        union { __hip_bfloat16 h[4]; uint2 u; } o;
        o.h[0]=__float2bfloat16(v.x); o.h[1]=__float2bfloat16(v.y);
        o.h[2]=__float2bfloat16(v.z); o.h[3]=__float2bfloat16(v.w);
        ((uint2*)xb)[(size_t)m*256 + e4] = o.u;
    } else if (i < 2883584) {                // qkv_w conv (786432 float4)
        const long j = i - 2097152;
        float4 v = ((const float4*)qkv_w)[j];
        union { __hip_bfloat16 h[4]; uint2 u; } o;
        o.h[0]=__float2bfloat16(v.x); o.h[1]=__float2bfloat16(v.y);
        o.h[2]=__float2bfloat16(v.z); o.h[3]=__float2bfloat16(v.w);
        ((uint2*)qwb)[j] = o.u;
    } else if (i < 3145728) {                // out_w conv (262144 float4)
        const long j = i - 2883584;
        float4 v = ((const float4*)out_w)[j];
        union { __hip_bfloat16 h[4]; uint2 u; } o;
        o.h[0]=__float2bfloat16(v.x); o.h[1]=__float2bfloat16(v.y);
        o.h[2]=__float2bfloat16(v.z); o.h[3]=__float2bfloat16(v.w);
        ((uint2*)owb)[j] = o.u;
    }
}

// ---------------- GEMM 1: QKV projection, bf16 MFMA, scatter epilogue ----------------
// Q stored pre-scaled by QSCALE.
__global__ __launch_bounds__(256) void gemm_qkv(
    const __hip_bfloat16* __restrict__ A, const __hip_bfloat16* __restrict__ Bw,
    const float* __restrict__ bias,
    __hip_bfloat16* __restrict__ Qp, __hip_bfloat16* __restrict__ Kp,
    __hip_bfloat16* __restrict__ Vt)
{
    __shared__ __align__(16) __hip_bfloat16 As[128*32];
    __shared__ __align__(16) __hip_bfloat16 Bs[128*32];
    const int t = threadIdx.x;
    const int l = t & 63, lm = l & 15, quad = l >> 4;
    const int w = t >> 6;
    const int mw = (w & 1)*64, nw = (w >> 1)*64;
    const int m0 = blockIdx.y*128, n0 = blockIdx.x*128;

    const int srow = t >> 2;              // 0..63
    const int scol = (t & 3)*8;
    const __hip_bfloat16* ag = A  + (size_t)(m0 + srow)*1024 + scol;
    const __hip_bfloat16* bg = Bw + (size_t)(n0 + srow)*1024 + scol;
    __hip_bfloat16* al = As + t*8;
    __hip_bfloat16* bl = Bs + t*8;

    f32x4 acc[4][4] = {};
    for (int k0 = 0; k0 < 1024; k0 += 32) {
        __syncthreads();
        gld16(ag + k0, al);
        gld16(ag + (size_t)64*1024 + k0, al + 2048);
        gld16(bg + k0, bl);
        gld16(bg + (size_t)64*1024 + k0, bl + 2048);
        __syncthreads();
        bhalf8 af[4], bf[4];
#pragma unroll
        for (int i = 0; i < 4; i++) {
            af[i] = *(const bhalf8*)&As[(mw + i*16 + lm)*32 + quad*8];
            bf[i] = *(const bhalf8*)&Bs[(nw + i*16 + lm)*32 + quad*8];
        }
#pragma unroll
        for (int mf = 0; mf < 4; mf++)
#pragma unroll
            for (int nf = 0; nf < 4; nf++)
                acc[mf][nf] = __builtin_amdgcn_mfma_f32_16x16x32_bf16(af[mf], bf[nf], acc[mf][nf], 0,0,0);
    }
#pragma unroll
    for (int nf = 0; nf < 4; nf++) {
        const int n = n0 + nw + nf*16 + lm;
        const float bz = bias[n];
        const int which = n >> 10, hh = (n >> 6) & 15, dd = n & 63;
#pragma unroll
        for (int mf = 0; mf < 4; mf++)
#pragma unroll
            for (int r = 0; r < 4; r++) {
                const int m = m0 + mw + mf*16 + quad*4 + r;
                const int b2 = m >> 11, s2 = m & 2047;
                const float vf = acc[mf][nf][r] + bz;
                if (which == 0)
                    Qp[((size_t)(b2*Hh + hh)*Sq + s2)*Dd + dd] = __float2bfloat16(vf * QSCALE);
                else if (which == 1)
                    Kp[((size_t)(b2*Hh + hh)*Sq + s2)*Dd + dd] = __float2bfloat16(vf);
                else
                    Vt[((size_t)(b2*Hh + hh)*Dd + dd)*Sq + s2] = __float2bfloat16(vf);
            }
    }
}

// ---------------- Attention core: LDS-staged tiles, XCD-pinned ----------------
// blk = xcd + 8*qt + 256*grp ; bh = grp*8 + xcd. Block = 4 waves x 16 q rows.
// Per kt: K tile (8KB, global-contiguous) + V^T tile (8KB) staged into swizzled
// frag-major LDS; all frag reads are ds_read_b128 at lane*16B (conflict-free).
__global__ __launch_bounds__(256, 4) void attn_mfma(
    const __hip_bfloat16* __restrict__ Qp, const __hip_bfloat16* __restrict__ Kp,
    const __hip_bfloat16* __restrict__ Vt,
    const float* __restrict__ am, const unsigned char* __restrict__ kpm,
    const unsigned int* __restrict__ flag,
    __hip_bfloat16* __restrict__ wa, float* __restrict__ rlbuf)
{
    __shared__ __align__(16) __hip_bfloat16 Ks[4096];
    __shared__ __align__(16) __hip_bfloat16 Vs[4096];
    const int t = threadIdx.x;
    const int w = t >> 6, l = t & 63, lm = l & 15, quad = l >> 4;
    const int blk = blockIdx.x;
    const int xcd = blk & 7;
    const int qt  = (blk >> 3) & 31;
    const int grp = blk >> 8;                  // 0..3
    const int bh  = grp*8 + xcd;
    const int b   = bh >> 4, h = bh & 15;
    const int q   = qt*64 + w*16 + lm;
    const bool masked = (flag[0] != 0u);

    const __hip_bfloat16* qbase = Qp + (size_t)bh*Sq*Dd;
    const __hip_bfloat16* kbase = Kp + (size_t)bh*Sq*Dd;
    const __hip_bfloat16* vbase = Vt + (size_t)bh*Dd*Sq;

    // Q as B-operand (pre-scaled), one-time strided load
    bhalf8 bq[2];
    bq[0] = *(const bhalf8*)(qbase + (size_t)q*Dd + quad*8);
    bq[1] = *(const bhalf8*)(qbase + (size_t)q*Dd + quad*8 + 32);

    f32x4 o[4] = {};
    float lsum = 0.f;

    // LDS write offsets for this thread's two slots
    const int off0 = tile_off(t), off1 = tile_off(t + 256);

    // preload tile 0 staging regs (global-linear: slot s -> elem s*8)
    uint4 kreg0 = *(const uint4*)(kbase + (size_t)t*8);
    uint4 kreg1 = *(const uint4*)(kbase + (size_t)(t + 256)*8);
    uint4 vreg0 = *(const uint4*)(vbase + (size_t)(t >> 3)*Sq + (t & 7)*8);
    uint4 vreg1 = *(const uint4*)(vbase + (size_t)((t + 256) >> 3)*Sq + (t & 7)*8);

    for (int kt = 0; kt < 32; kt++) {
        __syncthreads();                       // previous tile's readers done
        *(uint4*)&Ks[off0] = kreg0;
        *(uint4*)&Ks[off1] = kreg1;
        *(uint4*)&Vs[off0] = vreg0;
        *(uint4*)&Vs[off1] = vreg1;
        if (kt < 31) {                         // prefetch tile kt+1
            const int kn = (kt + 1)*64;
            kreg0 = *(const uint4*)(kbase + (size_t)kn*Dd + t*8);
            kreg1 = *(const uint4*)(kbase + (size_t)kn*Dd + (t + 256)*8);
            vreg0 = *(const uint4*)(vbase + (size_t)(t >> 3)*Sq + kn + (t & 7)*8);
            vreg1 = *(const uint4*)(vbase + (size_t)((t + 256) >> 3)*Sq + kn + (t & 7)*8);
        }
        __syncthreads();                       // tile kt visible

        const int k0 = kt*64;
        // S^T = K · Q^T
        f32x4 s[4] = {};
#pragma unroll
        for (int f = 0; f < 2; f++) {
            bhalf8 ak[4];
#pragma unroll
            for (int j = 0; j < 4; j++)
                ak[j] = *(const bhalf8*)&Ks[f*2048 + j*512 + l*8];
#pragma unroll
            for (int j = 0; j < 4; j++)
                s[j] = __builtin_amdgcn_mfma_f32_16x16x32_bf16(ak[j], bq[f], s[j], 0,0,0);
        }

        // exp2 + pack (lane holds keys k0 + j*16 + quad*4 + r for its q)
        int pk[4][2];
#pragma unroll
        for (int j = 0; j < 4; j++) {
            float p[4];
#pragma unroll
            for (int r = 0; r < 4; r++) {
                float sv = s[j][r];
                if (masked) {
                    const int key = k0 + j*16 + quad*4 + r;
                    const float km = kpm[b*Sq + key] ? -1e30f : 0.0f;
                    sv += (am[(size_t)q*Sq + key] + km) * LOG2E;
                }
                p[r] = exp2f(sv);
            }
            lsum += (p[0]+p[1]) + (p[2]+p[3]);
            pk[j][0] = pkbf(p[0], p[1]);
            pk[j][1] = pkbf(p[2], p[3]);
        }

        // PV: O^T += V^T · P^T (P^T B-frags via cross-lane pull)
#pragma unroll
        for (int ks = 0; ks < 2; ks++) {
            union { int i[4]; bhalf8 v; } bp;
#pragma unroll
            for (int g = 0; g < 4; g++) {
                const int src = (2*(quad & 1) + (g >> 1))*16 + lm;
                const int t0 = __shfl(pk[2*ks    ][g & 1], src, 64);
                const int t1 = __shfl(pk[2*ks + 1][g & 1], src, 64);
                bp.i[g] = (quad >= 2) ? t1 : t0;
            }
            bhalf8 av[4];
#pragma unroll
            for (int nd = 0; nd < 4; nd++)
                av[nd] = *(const bhalf8*)&Vs[ks*2048 + nd*512 + l*8];
#pragma unroll
            for (int nd = 0; nd < 4; nd++)
                o[nd] = __builtin_amdgcn_mfma_f32_16x16x32_bf16(av[nd], bp.v, o[nd], 0,0,0);
        }
    }

    lsum += __shfl_xor(lsum, 16, 64);
    lsum += __shfl_xor(lsum, 32, 64);
    const float rl = 1.0f / lsum;
    if (quad == 0) rlbuf[(size_t)bh*Sq + q] = rl;

#pragma unroll
    for (int nd = 0; nd < 4; nd++) {
        union { __hip_bfloat16 hx[4]; uint2 u; } ou;
#pragma unroll
        for (int r = 0; r < 4; r++) ou.hx[r] = __float2bfloat16(o[nd][r] * rl);
        *(uint2*)(wa + ((size_t)b*Sq + q)*Ee + h*Dd + nd*16 + quad*4) = ou.u;
    }
}

// ---------------- attn_mean: block = (b, 128 q, 64 shared keys), LDS-staged ----------------
// Wave w owns q rows [q0 + w*32, +32) (2 su subtiles). K tile shared, Q tiles per wave.
__global__ __launch_bounds__(256, 4) void attn_mean_k(
    const __hip_bfloat16* __restrict__ Qp, const __hip_bfloat16* __restrict__ Kp,
    const float* __restrict__ am, const unsigned char* __restrict__ kpm,
    const unsigned int* __restrict__ flag,
    const float* __restrict__ rlbuf, float* __restrict__ attn_mean)
{
    __shared__ __align__(16) __hip_bfloat16 Ks[4096];   // 64 keys x 64 d
    __shared__ __align__(16) __hip_bfloat16 Qs[8192];   // 4 waves x 32 q x 64 d
    const int t = threadIdx.x;
    const int w = t >> 6, l = t & 63, lm = l & 15, quad = l >> 4;
    const int b  = blockIdx.z;
    const int q0 = blockIdx.y * 128;
    const int kc = blockIdx.x * 64;
    const int q0w = q0 + w*32;
    const bool masked = (flag[0] != 0u);

    const int koff = tile_off(t);           // K slots: t (256 of 512 -> t, t+256)
    const int koff1 = tile_off(t + 256);
    // Q slots: 1024; thread handles t, t+256, t+512, t+768
    int qoff[4];
#pragma unroll
    for (int i = 0; i < 4; i++) {
        const int s = t + i*256;
        qoff[i] = (s >> 8)*2048 + ((s >> 7) & 1)*1024 + ((s >> 2) & 1)*512
                + (s & 3)*128 + ((s >> 3) & 15)*8;
    }

    float macc[2][4][4] = {};

    // preload head 0 staging regs
    const __hip_bfloat16* kb0 = Kp + ((size_t)(b*Hh)*Sq + kc)*Dd;
    const __hip_bfloat16* qb0 = Qp + ((size_t)(b*Hh)*Sq + q0)*Dd;
    uint4 kr0 = *(const uint4*)(kb0 + (size_t)t*8);
    uint4 kr1 = *(const uint4*)(kb0 + (size_t)(t + 256)*8);
    uint4 qr[4];
#pragma unroll
    for (int i = 0; i < 4; i++) qr[i] = *(const uint4*)(qb0 + (size_t)(t + i*256)*8);

    for (int h = 0; h < Hh; h++) {
        __syncthreads();
        *(uint4*)&Ks[koff]  = kr0;
        *(uint4*)&Ks[koff1] = kr1;
#pragma unroll
        for (int i = 0; i < 4; i++) *(uint4*)&Qs[qoff[i]] = qr[i];
        if (h < Hh-1) {
            const __hip_bfloat16* kbn = Kp + ((size_t)(b*Hh + h+1)*Sq + kc)*Dd;
            const __hip_bfloat16* qbn = Qp + ((size_t)(b*Hh + h+1)*Sq + q0)*Dd;
            kr0 = *(const uint4*)(kbn + (size_t)t*8);
            kr1 = *(const uint4*)(kbn + (size_t)(t + 256)*8);
#pragma unroll
            for (int i = 0; i < 4; i++) qr[i] = *(const uint4*)(qbn + (size_t)(t + i*256)*8);
        }
        __syncthreads();

        const int bh = b*Hh + h;
        bhalf8 bk[8];
#pragma unroll
        for (int f = 0; f < 2; f++)
#pragma unroll
            for (int j = 0; j < 4; j++)
                bk[f*4+j] = *(const bhalf8*)&Ks[f*2048 + j*512 + l*8];

#pragma unroll
        for (int su = 0; su < 2; su++) {
            f32x4 s[4] = {};
#pragma unroll
            for (int f = 0; f < 2; f++) {
                bhalf8 aq = *(const bhalf8*)&Qs[w*2048 + su*1024 + f*512 + l*8];
#pragma unroll
                for (int j = 0; j < 4; j++)
                    s[j] = __builtin_amdgcn_mfma_f32_16x16x32_bf16(aq, bk[f*4+j], s[j], 0,0,0);
            }
            float rl4[4];
#pragma unroll
            for (int r = 0; r < 4; r++)
                rl4[r] = rlbuf[(size_t)bh*Sq + q0w + su*16 + quad*4 + r] * 0.0625f;
#pragma unroll
            for (int j = 0; j < 4; j++)
#pragma unroll
                for (int r = 0; r < 4; r++) {
                    float sv = s[j][r];
                    if (masked) {
                        const int key = kc + j*16 + lm;
                        const float km = kpm[b*Sq + key] ? -1e30f : 0.0f;
                        sv += (am[(size_t)(q0w + su*16 + quad*4 + r)*Sq + key] + km) * LOG2E;
                    }
                    macc[su][j][r] += exp2f(sv) * rl4[r];
                }
        }
    }
#pragma unroll
    for (int su = 0; su < 2; su++)
#pragma unroll
        for (int j = 0; j < 4; j++)
#pragma unroll
            for (int r = 0; r < 4; r++)
                attn_mean[((size_t)b*Sq + q0w + su*16 + quad*4 + r)*Sq + kc + j*16 + lm] =
                    macc[su][j][r];
}

// ---------------- GEMM 2: output projection, bf16 MFMA ----------------
__global__ __launch_bounds__(256) void gemm_out(
    const __hip_bfloat16* __restrict__ A, const __hip_bfloat16* __restrict__ Bw,
    const float* __restrict__ bias, float* __restrict__ outp)
{
    __shared__ __align__(16) __hip_bfloat16 As[128*32];
    __shared__ __align__(16) __hip_bfloat16 Bs[128*32];
    const int t = threadIdx.x;
    const int l = t & 63, lm = l & 15, quad = l >> 4;
    const int w = t >> 6;
    const int mw = (w & 1)*64, nw = (w >> 1)*64;
    const int m0 = blockIdx.y*128, n0 = blockIdx.x*128;

    const int srow = t >> 2;
    const int scol = (t & 3)*8;
    const __hip_bfloat16* ag = A  + (size_t)(m0 + srow)*1024 + scol;
    const __hip_bfloat16* bg = Bw + (size_t)(n0 + srow)*1024 + scol;
    __hip_bfloat16* al = As + t*8;
    __hip_bfloat16* bl = Bs + t*8;

    f32x4 acc[4][4] = {};
    for (int k0 = 0; k0 < 1024; k0 += 32) {
        __syncthreads();
        gld16(ag + k0, al);
        gld16(ag + (size_t)64*1024 + k0, al + 2048);
        gld16(bg + k0, bl);
        gld16(bg + (size_t)64*1024 + k0, bl + 2048);
        __syncthreads();
        bhalf8 af[4], bf[4];
#pragma unroll
        for (int i = 0; i < 4; i++) {
            af[i] = *(const bhalf8*)&As[(mw + i*16 + lm)*32 + quad*8];
            bf[i] = *(const bhalf8*)&Bs[(nw + i*16 + lm)*32 + quad*8];
        }
#pragma unroll
        for (int mf = 0; mf < 4; mf++)
#pragma unroll
            for (int nf = 0; nf < 4; nf++)
                acc[mf][nf] = __builtin_amdgcn_mfma_f32_16x16x32_bf16(af[mf], bf[nf], acc[mf][nf], 0,0,0);
    }
#pragma unroll
    for (int nf = 0; nf < 4; nf++) {
        const int n = n0 + nw + nf*16 + lm;
        const float bz = bias[n];
#pragma unroll
        for (int mf = 0; mf < 4; mf++)
#pragma unroll
            for (int r = 0; r < 4; r++) {
                const int m = m0 + mw + mf*16 + quad*4 + r;
                const int b2 = m >> 11, s2 = m & 2047;
                outp[((size_t)s2*Bb + b2)*Ee + n] = acc[mf][nf][r] + bz;
            }
    }
}

extern "C" void kernel_launch(void* const* d_in, const int* in_sizes, int n_in,
                              void* d_out, int out_size, void* d_ws, size_t ws_size,
                              hipStream_t stream) {
    const float*         x         = (const float*)d_in[0];
    const float*         attn_mask = (const float*)d_in[1];
    const unsigned char* kpm       = (const unsigned char*)d_in[2];
    const float*         qkv_w     = (const float*)d_in[3];
    const float*         qkv_b     = (const float*)d_in[4];
    const float*         out_w     = (const float*)d_in[5];
    const float*         out_b     = (const float*)d_in[6];

    float* outp      = (float*)d_out;
    float* attn_mean = outp + 4194304;          // S*B*E

    __hip_bfloat16* xb  = (__hip_bfloat16*)d_ws;     // 8 MB
    __hip_bfloat16* qwb = xb  + 4194304;             // 6 MB
    __hip_bfloat16* owb = qwb + 3145728;             // 2 MB
    __hip_bfloat16* Qp  = owb + 1048576;             // 8 MB (pre-scaled by QSCALE)
    __hip_bfloat16* Kp  = Qp  + 4194304;             // 8 MB
    __hip_bfloat16* Vt  = Kp  + 4194304;             // 8 MB (transposed [B,H,D,S])
    __hip_bfloat16* wab = Vt  + 4194304;             // 8 MB
    float* rlbuf        = (float*)(wab + 4194304);   // 256 KB
    unsigned int* flag  = (unsigned int*)(rlbuf + 65536);

    hipMemsetAsync(flag, 0, sizeof(unsigned int), stream);
    prep_k<<<12288, 256, 0, stream>>>(x, attn_mask, (const unsigned int*)kpm,
                                      qkv_w, out_w, xb, qwb, owb, flag);
    gemm_qkv<<<dim3(24, 32), 256, 0, stream>>>(xb, qwb, qkv_b, Qp, Kp, Vt);
    attn_mfma<<<dim3(1024), 256, 0, stream>>>(Qp, Kp, Vt, attn_mask, kpm, flag, wab, rlbuf);
    attn_mean_k<<<dim3(32, 16, Bb), 256, 0, stream>>>(Qp, Kp, attn_mask, kpm, flag, rlbuf, attn_mean);
    gemm_out<<<dim3(8, 32), 256, 0, stream>>>(wab, owb, out_b, outp);
}